// Round 6
// baseline (1214.016 us; speedup 1.0000x reference)
//
#include <hip/hip_runtime.h>
#include <hip/hip_fp16.h>
#include <cstdint>

#define N_VOX   200000
#define N_PAIRS 100000
#define KK      27
#define INC     64
#define OUTC    64
#define BN_EPS  1e-5f

// Binning geometry: partition output rows into chunks of 128 (part = row >> 7)
#define ROWS_PER_PART 128
#define NPART         1563             // ceil(200000/128)
#define NBIN          (KK * NPART)     // 42201
#define BIN_CAP       96               // avg 64, sigma 8 -> +4 sigma; ovf_fix catches the rest
#define OVF_CAP       4096
#define YSTRIDE       68               // LDS row stride (floats), breaks bank pattern

typedef __attribute__((ext_vector_type(8))) short bf16x8;
typedef __attribute__((ext_vector_type(4))) float f32x4;

__device__ inline uint32_t cvt_pk_bf16(float lo, float hi) {
    uint32_t r;
    asm("v_cvt_pk_bf16_f32 %0, %1, %2" : "=v"(r) : "v"(lo), "v"(hi));
    return r;
}

__device__ inline bf16x8 pack_frag(float a, float b, float c, float d,
                                   float e, float f, float g, float h) {
    union { uint32_t u[4]; bf16x8 v; } cv;
    cv.u[0] = cvt_pk_bf16(a, b);
    cv.u[1] = cvt_pk_bf16(c, d);
    cv.u[2] = cvt_pk_bf16(e, f);
    cv.u[3] = cvt_pk_bf16(g, h);
    return cv.v;
}

__device__ inline bf16x8 as_frag(uint4 u) {
    union { uint4 u; bf16x8 v; } cv; cv.u = u; return cv.v;
}

// ---------------------------------------------------------------------------
// Cast x (f32) -> xb (bf16), row-major [N_VOX][64], row = 128 B.
// ---------------------------------------------------------------------------
__global__ __launch_bounds__(256) void xcast(
    const float* __restrict__ x, uint4* __restrict__ xb)
{
    const size_t total = (size_t)N_VOX * 8;        // 8-float groups
    size_t i = (size_t)blockIdx.x * blockDim.x + threadIdx.x;
    const size_t stride = (size_t)gridDim.x * blockDim.x;
    for (; i < total; i += stride) {
        const float4 a = *(const float4*)(x + i * 8);
        const float4 b = *(const float4*)(x + i * 8 + 4);
        uint4 o;
        o.x = cvt_pk_bf16(a.x, a.y);
        o.y = cvt_pk_bf16(a.z, a.w);
        o.z = cvt_pk_bf16(b.x, b.y);
        o.w = cvt_pk_bf16(b.z, b.w);
        xb[i] = o;
    }
}

// ---------------------------------------------------------------------------
// Pre-pack w into bf16 B-fragment layout: frag fid=(k*4+n)*2+kk, lane l holds
// B[kbase + (l>>4)*8 + j][n*16 + (l&15)], stored as uint4 at wp[fid*64 + l].
// ---------------------------------------------------------------------------
__global__ __launch_bounds__(256) void pack_w(
    const float* __restrict__ w, uint4* __restrict__ wp)
{
    const int tid = blockIdx.x * blockDim.x + threadIdx.x;
    if (tid >= KK * 8 * 64) return;
    const int lane = tid & 63;
    const int fid  = tid >> 6;
    const int k    = fid >> 3;
    const int n    = (fid & 7) >> 1;
    const int kk   = fid & 1;
    const int row  = lane & 15;
    const int kg   = lane >> 4;
    const int kbase = kk * 32 + kg * 8;

    const float* bp = w + (size_t)k * (INC * OUTC) + (size_t)kbase * OUTC + n * 16 + row;
    bf16x8 f = pack_frag(bp[0*OUTC], bp[1*OUTC], bp[2*OUTC], bp[3*OUTC],
                         bp[4*OUTC], bp[5*OUTC], bp[6*OUTC], bp[7*OUTC]);
    union { bf16x8 v; uint4 u; } cv; cv.v = f;
    wp[(size_t)fid * 64 + lane] = cv.u;
}

// ---------------------------------------------------------------------------
// Bin the 2.7M (k,pair) entries into fixed-capacity (k,part) bins.
// Record = in_idx (18 bits) | local_row << 18 (7 bits). blockIdx.y = k.
// ---------------------------------------------------------------------------
__global__ __launch_bounds__(256) void scatter_pairs(
    const int* __restrict__ kin, const int* __restrict__ kout,
    uint32_t* __restrict__ cnt, uint32_t* __restrict__ bins,
    uint32_t* __restrict__ ovf_cnt, uint32_t* __restrict__ ovf)
{
    const int k = blockIdx.y;
    const int i = blockIdx.x * blockDim.x + threadIdx.x;
    if (i >= N_PAIRS) return;
    const int idx = k * N_PAIRS + i;
    const int out = kout[idx];
    const int in  = kin[idx];
    const int part  = out >> 7;
    const int local = out & 127;
    const int bin   = k * NPART + part;
    const uint32_t pos = atomicAdd(&cnt[bin], 1u);
    if (pos < BIN_CAP) {
        bins[(size_t)bin * BIN_CAP + pos] = (uint32_t)in | ((uint32_t)local << 18);
    } else {
        const uint32_t p2 = atomicAdd(ovf_cnt, 1u);
        if (p2 < OVF_CAP) ovf[p2] = (uint32_t)idx;
    }
}

// ---------------------------------------------------------------------------
// Binned conv, bf16-x, software-pipelined. Block = one 128-row partition in
// LDS (stride 68). Wave wid owns k = wid, wid+8, ... B-frags in 8 named regs;
// next chunk's recs + x rows prefetched into named regs during MFMA+ds of the
// current chunk. No global atomics; coalesced store-flush.
// ---------------------------------------------------------------------------
__global__ __launch_bounds__(512) void conv_part(
    const char* __restrict__ xbytes, const uint4* __restrict__ wp,
    const uint32_t* __restrict__ cnt, const uint32_t* __restrict__ bins,
    float* __restrict__ y)
{
    __shared__ __align__(16) float yloc[ROWS_PER_PART * YSTRIDE];   // 34816 B
    __shared__ int sh_cnt[KK];

    const int tid  = threadIdx.x;
    const int lane = tid & 63;
    const int wid  = tid >> 6;            // 0..7
    const int row  = lane & 15;
    const int kg   = lane >> 4;
    const int part = blockIdx.x;

    {
        const float4 z = {0.f, 0.f, 0.f, 0.f};
        float4* p = (float4*)yloc;
        #pragma unroll
        for (int i = 0; i < 5; ++i) {
            const int idx = tid + i * 512;
            if (idx < ROWS_PER_PART * YSTRIDE / 4) p[idx] = z;
        }
    }
    if (tid < KK) {
        const uint32_t c = cnt[tid * NPART + part];
        sh_cnt[tid] = (int)(c < BIN_CAP ? c : BIN_CAP);
    }
    __syncthreads();

    for (int k = wid; k < KK; k += 8) {
        const int cntk = sh_cnt[k];
        if (cntk == 0) continue;

        // B fragments for this k: 8 named regs (L2-hot)
        const size_t fb = (size_t)(k * 8) * 64 + lane;
        const uint4 b0 = wp[fb];        const uint4 b1 = wp[fb + 64];
        const uint4 b2 = wp[fb + 128];  const uint4 b3 = wp[fb + 192];
        const uint4 b4 = wp[fb + 256];  const uint4 b5 = wp[fb + 320];
        const uint4 b6 = wp[fb + 384];  const uint4 b7 = wp[fb + 448];

        const uint32_t* base = bins + (size_t)(k * NPART + part) * BIN_CAP;
        const int nch = (cntk + 15) >> 4;

        // ---- prologue: chunk 0 recs + x rows ----
        uint32_t rin0 = base[row];
        uint4    rout0 = *(const uint4*)(base + kg * 4);
        int id0 = min((int)(rin0 & 0x3FFFFu), N_VOX - 1);
        const char* xp0 = xbytes + (size_t)id0 * 128 + kg * 16;
        uint4 xlo0 = *(const uint4*)(xp0);
        uint4 xhi0 = *(const uint4*)(xp0 + 64);

        for (int ch = 0; ch < nch; ++ch) {
            const int count = cntk - ch * 16;

            // ---- prefetch chunk ch+1 ----
            uint32_t rin1 = 0;
            uint4 rout1 = {0,0,0,0}, xlo1 = {0,0,0,0}, xhi1 = {0,0,0,0};
            if (ch + 1 < nch) {
                const uint32_t* bnext = base + (ch + 1) * 16;
                rin1  = bnext[row];
                rout1 = *(const uint4*)(bnext + kg * 4);
                const int id1 = min((int)(rin1 & 0x3FFFFu), N_VOX - 1);
                const char* xp1 = xbytes + (size_t)id1 * 128 + kg * 16;
                xlo1 = *(const uint4*)(xp1);
                xhi1 = *(const uint4*)(xp1 + 64);
            }

            // ---- MFMA on current chunk ----
            const bf16x8 a0 = as_frag(xlo0);
            const bf16x8 a1 = as_frag(xhi0);
            f32x4 c0 = {0,0,0,0}, c1 = {0,0,0,0}, c2 = {0,0,0,0}, c3 = {0,0,0,0};
            c0 = __builtin_amdgcn_mfma_f32_16x16x32_bf16(a0, as_frag(b0), c0, 0, 0, 0);
            c0 = __builtin_amdgcn_mfma_f32_16x16x32_bf16(a1, as_frag(b1), c0, 0, 0, 0);
            c1 = __builtin_amdgcn_mfma_f32_16x16x32_bf16(a0, as_frag(b2), c1, 0, 0, 0);
            c1 = __builtin_amdgcn_mfma_f32_16x16x32_bf16(a1, as_frag(b3), c1, 0, 0, 0);
            c2 = __builtin_amdgcn_mfma_f32_16x16x32_bf16(a0, as_frag(b4), c2, 0, 0, 0);
            c2 = __builtin_amdgcn_mfma_f32_16x16x32_bf16(a1, as_frag(b5), c2, 0, 0, 0);
            c3 = __builtin_amdgcn_mfma_f32_16x16x32_bf16(a0, as_frag(b6), c3, 0, 0, 0);
            c3 = __builtin_amdgcn_mfma_f32_16x16x32_bf16(a1, as_frag(b7), c3, 0, 0, 0);

            // ---- LDS scatter for current chunk ----
            const uint32_t r0 = rout0.x, r1 = rout0.y, r2 = rout0.z, r3 = rout0.w;
            #pragma unroll
            for (int j = 0; j < 4; ++j) {
                const uint32_t rj = (j == 0) ? r0 : (j == 1) ? r1 : (j == 2) ? r2 : r3;
                if (kg * 4 + j < count) {
                    const int local = (int)((rj >> 18) & 127u);
                    float* lb = &yloc[local * YSTRIDE + row];
                    __hip_atomic_fetch_add(lb + 0,  c0[j], __ATOMIC_RELAXED, __HIP_MEMORY_SCOPE_WORKGROUP);
                    __hip_atomic_fetch_add(lb + 16, c1[j], __ATOMIC_RELAXED, __HIP_MEMORY_SCOPE_WORKGROUP);
                    __hip_atomic_fetch_add(lb + 32, c2[j], __ATOMIC_RELAXED, __HIP_MEMORY_SCOPE_WORKGROUP);
                    __hip_atomic_fetch_add(lb + 48, c3[j], __ATOMIC_RELAXED, __HIP_MEMORY_SCOPE_WORKGROUP);
                }
            }

            // rotate pipeline
            rin0 = rin1; rout0 = rout1; xlo0 = xlo1; xhi0 = xhi1;
        }
    }

    __syncthreads();
    // coalesced flush (store): rows [part*128, part*128+128) ∩ [0, N_VOX)
    const int grow0 = part * ROWS_PER_PART;
    float4* yg = (float4*)(y + (size_t)grow0 * OUTC);
    #pragma unroll
    for (int i = 0; i < 4; ++i) {
        const int i4 = tid + i * 512;              // 0..2047
        const int r  = i4 >> 4;
        const int c4 = i4 & 15;
        if (grow0 + r < N_VOX)
            yg[i4] = *(const float4*)(yloc + r * YSTRIDE + c4 * 4);
    }
}

// ---------------------------------------------------------------------------
// Overflow fixup (expected ~0-5 entries): direct matvec + global atomic add.
// Runs after conv_part's flush.
// ---------------------------------------------------------------------------
__global__ void ovf_fix(
    const float* __restrict__ x, const float* __restrict__ w,
    const int* __restrict__ kin, const int* __restrict__ kout,
    const uint32_t* __restrict__ ovf_cnt, const uint32_t* __restrict__ ovf,
    float* __restrict__ y)
{
    const int t = threadIdx.x;                 // 64 threads, t = channel
    const int n = (int)min(*ovf_cnt, (uint32_t)OVF_CAP);
    for (int i = 0; i < n; ++i) {
        const int idx = (int)ovf[i];
        const int k   = idx / N_PAIRS;
        const int in  = kin[idx];
        const int out = kout[idx];
        float acc = 0.f;
        for (int d = 0; d < INC; ++d)
            acc = fmaf(x[(size_t)in * INC + d], w[(size_t)k * INC * OUTC + d * OUTC + t], acc);
        unsafeAtomicAdd(&y[(size_t)out * OUTC + t], acc);
    }
}

// ---------------------------------------------------------------------------
// BN stats / finalize / apply (f32, y in d_out)
// ---------------------------------------------------------------------------
__global__ __launch_bounds__(256) void bn_reduce(
    const float* __restrict__ y, float* __restrict__ stats)
{
    __shared__ float s_sum[256];
    __shared__ float s_sq[256];

    const int c = threadIdx.x & 63;
    const int row0 = (blockIdx.x * blockDim.x + threadIdx.x) >> 6;
    const int rstride = (gridDim.x * blockDim.x) >> 6;

    float s = 0.f, ss = 0.f;
    for (int r = row0; r < N_VOX; r += rstride) {
        const float v = y[(size_t)r * OUTC + c];
        s += v;
        ss += v * v;
    }
    s_sum[threadIdx.x] = s;
    s_sq[threadIdx.x]  = ss;
    __syncthreads();

    if (threadIdx.x < 64) {
        const float ts  = (s_sum[c] + s_sum[64 + c]) + (s_sum[128 + c] + s_sum[192 + c]);
        const float tss = (s_sq[c]  + s_sq[64 + c])  + (s_sq[128 + c]  + s_sq[192 + c]);
        atomicAdd(&stats[c], ts);
        atomicAdd(&stats[64 + c], tss);
    }
}

__global__ void bn_finalize(
    const float* __restrict__ stats, const float* __restrict__ gamma,
    const float* __restrict__ beta, float* __restrict__ coef)
{
    const int c = threadIdx.x;
    if (c < 64) {
        const float inv_n = 1.0f / (float)N_VOX;
        const float mean  = stats[c] * inv_n;
        const float var   = stats[64 + c] * inv_n - mean * mean;
        const float scale = gamma[c] * rsqrtf(var + BN_EPS);
        coef[c]      = scale;
        coef[64 + c] = beta[c] - mean * scale;
    }
}

__global__ __launch_bounds__(256) void bn_apply(
    float* __restrict__ y, const float* __restrict__ coef)
{
    const size_t total4 = (size_t)N_VOX * OUTC / 4;
    size_t i = (size_t)blockIdx.x * blockDim.x + threadIdx.x;
    const size_t stride = (size_t)gridDim.x * blockDim.x;

    const int c0 = (int)((i * 4) & 63);
    const float sc0 = coef[c0 + 0], sh0 = coef[64 + c0 + 0];
    const float sc1 = coef[c0 + 1], sh1 = coef[64 + c0 + 1];
    const float sc2 = coef[c0 + 2], sh2 = coef[64 + c0 + 2];
    const float sc3 = coef[c0 + 3], sh3 = coef[64 + c0 + 3];

    float4* y4 = (float4*)y;
    for (; i < total4; i += stride) {
        float4 v = y4[i];
        v.x = fmaxf(0.f, fmaf(v.x, sc0, sh0));
        v.y = fmaxf(0.f, fmaf(v.y, sc1, sh1));
        v.z = fmaxf(0.f, fmaf(v.z, sc2, sh2));
        v.w = fmaxf(0.f, fmaf(v.w, sc3, sh3));
        y4[i] = v;
    }
}

// ==================== fallback tier: fp16 pk-atomic path ====================
__global__ __launch_bounds__(256) void conv_mfma16(
    const float* __restrict__ x, const float* __restrict__ w,
    const int* __restrict__ kin, const int* __restrict__ kout,
    __half2* __restrict__ y2)
{
    const int lane = threadIdx.x & 63;
    const int wid  = threadIdx.x >> 6;
    const int k    = blockIdx.y;
    const int row  = lane & 15;
    const int kg   = lane >> 4;

    const float* wk = w + (size_t)k * (INC * OUTC);

    bf16x8 bfrag[4][2];
    #pragma unroll
    for (int n = 0; n < 4; ++n) {
        #pragma unroll
        for (int kk = 0; kk < 2; ++kk) {
            const int kbase = kk * 32 + kg * 8;
            const float* bp = wk + (size_t)kbase * OUTC + n * 16 + row;
            bfrag[n][kk] = pack_frag(bp[0*OUTC], bp[1*OUTC], bp[2*OUTC], bp[3*OUTC],
                                     bp[4*OUTC], bp[5*OUTC], bp[6*OUTC], bp[7*OUTC]);
        }
    }

    const int* kin_k  = kin  + (size_t)k * N_PAIRS;
    const int* kout_k = kout + (size_t)k * N_PAIRS;

    const int NCHUNK = N_PAIRS / 16;
    const int nwaves = gridDim.x * 4;

    for (int ch = blockIdx.x * 4 + wid; ch < NCHUNK; ch += nwaves) {
        const int e0 = ch * 16;
        const int in_idx = kin_k[e0 + row];
        const int4 oi = *(const int4*)(kout_k + e0 + kg * 4);

        const float* xr = x + (size_t)in_idx * INC + kg * 8;
        bf16x8 afrag[2];
        #pragma unroll
        for (int kk = 0; kk < 2; ++kk) {
            const f32x4 a0 = *(const f32x4*)(xr + kk * 32);
            const f32x4 a1 = *(const f32x4*)(xr + kk * 32 + 4);
            afrag[kk] = pack_frag(a0.x, a0.y, a0.z, a0.w, a1.x, a1.y, a1.z, a1.w);
        }

        f32x4 acc[4] = {{0,0,0,0},{0,0,0,0},{0,0,0,0},{0,0,0,0}};
        #pragma unroll
        for (int n = 0; n < 4; ++n) {
            acc[n] = __builtin_amdgcn_mfma_f32_16x16x32_bf16(afrag[0], bfrag[n][0], acc[n], 0, 0, 0);
            acc[n] = __builtin_amdgcn_mfma_f32_16x16x32_bf16(afrag[1], bfrag[n][1], acc[n], 0, 0, 0);
        }

        const int orow[4] = {oi.x, oi.y, oi.z, oi.w};
        #pragma unroll
        for (int j = 0; j < 4; ++j) {
            __half2* rbase = y2 + (size_t)orow[j] * (OUTC/2) + (row >> 1);
            #pragma unroll
            for (int n = 0; n < 4; ++n) {
                const float v = acc[n][j];
                const float p = __shfl_xor(v, 1);
                if (!(lane & 1)) {
                    __half2 h = __floats2half2_rn(v, p);
                    uint32_t u; __builtin_memcpy(&u, &h, 4);
                    __half2* addr = rbase + n * 8;
                    asm volatile("global_atomic_pk_add_f16 %0, %1, off"
                                 : : "v"(addr), "v"(u) : "memory");
                }
            }
        }
    }
}

__global__ __launch_bounds__(256) void bn_reduce16(
    const __half2* __restrict__ y2, float* __restrict__ stats)
{
    __shared__ float s0a[256], s1a[256], q0a[256], q1a[256];

    const int c2 = threadIdx.x & 31;
    const int row0 = (blockIdx.x * blockDim.x + threadIdx.x) >> 5;
    const int rstride = (gridDim.x * blockDim.x) >> 5;

    float s0 = 0.f, s1 = 0.f, q0 = 0.f, q1 = 0.f;
    for (int r = row0; r < N_VOX; r += rstride) {
        const float2 v = __half22float2(y2[(size_t)r * 32 + c2]);
        s0 += v.x; q0 += v.x * v.x;
        s1 += v.y; q1 += v.y * v.y;
    }
    s0a[threadIdx.x] = s0; s1a[threadIdx.x] = s1;
    q0a[threadIdx.x] = q0; q1a[threadIdx.x] = q1;
    __syncthreads();

    if (threadIdx.x < 64) {
        const int c = threadIdx.x, p = c >> 1, b = c & 1;
        float ts = 0.f, tq = 0.f;
        #pragma unroll
        for (int g = 0; g < 8; ++g) {
            ts += b ? s1a[g * 32 + p] : s0a[g * 32 + p];
            tq += b ? q1a[g * 32 + p] : q0a[g * 32 + p];
        }
        atomicAdd(&stats[c], ts);
        atomicAdd(&stats[64 + c], tq);
    }
}

__global__ __launch_bounds__(256) void bn_apply16(
    const __half2* __restrict__ y2, const float* __restrict__ coef,
    float2* __restrict__ out2)
{
    const size_t total2 = (size_t)N_VOX * 32;
    size_t i = (size_t)blockIdx.x * blockDim.x + threadIdx.x;
    const size_t stride = (size_t)gridDim.x * blockDim.x;

    const int c2 = (int)(i & 31);
    const float sc0 = coef[2*c2], sh0 = coef[64 + 2*c2];
    const float sc1 = coef[2*c2 + 1], sh1 = coef[64 + 2*c2 + 1];

    for (; i < total2; i += stride) {
        const float2 v = __half22float2(y2[i]);
        float2 o;
        o.x = fmaxf(0.f, fmaf(v.x, sc0, sh0));
        o.y = fmaxf(0.f, fmaf(v.y, sc1, sh1));
        out2[i] = o;
    }
}

extern "C" void kernel_launch(void* const* d_in, const int* in_sizes, int n_in,
                              void* d_out, int out_size, void* d_ws, size_t ws_size,
                              hipStream_t stream)
{
    const float* x     = (const float*)d_in[0];
    const float* w     = (const float*)d_in[1];
    const float* gamma = (const float*)d_in[2];
    const float* beta  = (const float*)d_in[3];
    const int*   kin   = (const int*)d_in[4];
    const int*   kout  = (const int*)d_in[5];

    float* y = (float*)d_out;

    // Tier A ws layout (bytes)
    const size_t off_xb    = 0;                                   // 25,600,000
    const size_t off_cnt   = 25600000;                            // 42201 u32 -> 168832
    const size_t off_ovfc  = 25768832;                            // 64
    const size_t off_ovf   = 25768896;                            // 16384
    const size_t off_stats = 25785280;                            // 512
    const size_t off_coef  = 25785792;                            // 512
    const size_t off_wp    = 25786304;                            // 221184
    const size_t off_bins  = 26007488;                            // 16,205,184
    const size_t needA     = off_bins + (size_t)NBIN * BIN_CAP * 4;   // ~42.2 MB

    const size_t y16_bytes = (size_t)N_VOX * OUTC * sizeof(__half);   // 25.6 MB
    const size_t needB = y16_bytes + 1024;

    if (ws_size >= needA) {
        uint4*    xb      = (uint4*)((char*)d_ws + off_xb);
        uint32_t* cnt     = (uint32_t*)((char*)d_ws + off_cnt);
        uint32_t* ovfc    = (uint32_t*)((char*)d_ws + off_ovfc);
        uint32_t* ovf     = (uint32_t*)((char*)d_ws + off_ovf);
        float*    stats   = (float*)((char*)d_ws + off_stats);
        float*    coef    = (float*)((char*)d_ws + off_coef);
        uint4*    wp      = (uint4*)((char*)d_ws + off_wp);
        uint32_t* bins    = (uint32_t*)((char*)d_ws + off_bins);

        hipMemsetAsync((char*)d_ws + off_cnt, 0, off_coef - off_cnt, stream);

        xcast<<<2048, 256, 0, stream>>>(x, xb);
        pack_w<<<54, 256, 0, stream>>>(w, wp);
        scatter_pairs<<<dim3((N_PAIRS + 255) / 256, KK), 256, 0, stream>>>(
            kin, kout, cnt, bins, ovfc, ovf);
        conv_part<<<NPART, 512, 0, stream>>>((const char*)xb, wp, cnt, bins, y);
        ovf_fix<<<1, 64, 0, stream>>>(x, w, kin, kout, ovfc, ovf, y);
        bn_reduce<<<512, 256, 0, stream>>>(y, stats);
        bn_finalize<<<1, 64, 0, stream>>>(stats, gamma, beta, coef);
        bn_apply<<<2048, 256, 0, stream>>>(y, coef);
    } else if (ws_size >= needB) {
        // fp16 packed-atomic path (proven 556 us conv)
        __half2* y2   = (__half2*)d_ws;
        float* stats  = (float*)((char*)d_ws + y16_bytes);
        float* coef   = stats + 128;

        hipMemsetAsync(y2, 0, y16_bytes, stream);
        hipMemsetAsync(stats, 0, 128 * sizeof(float), stream);

        conv_mfma16<<<dim3(64, KK), 256, 0, stream>>>(x, w, kin, kout, y2);
        bn_reduce16<<<512, 256, 0, stream>>>(y2, stats);
        bn_finalize<<<1, 64, 0, stream>>>(stats, gamma, beta, coef);
        bn_apply16<<<2048, 256, 0, stream>>>(y2, coef, (float2*)d_out);
    }
}

// Round 7
// 758.792 us; speedup vs baseline: 1.5999x; 1.5999x over previous
//
#include <hip/hip_runtime.h>
#include <hip/hip_fp16.h>
#include <cstdint>

#define N_VOX   200000
#define N_PAIRS 100000
#define KK      27
#define INC     64
#define OUTC    64
#define BN_EPS  1e-5f

// Binning geometry: partition INPUT rows into chunks of 128 (part = in >> 7)
#define ROWS_PER_PART 128
#define NPART         1563             // ceil(200000/128)
#define NBIN          (KK * NPART)     // 42201
#define BIN_CAP       96               // avg 64, +4 sigma; ovf_fix catches the rest
#define OVF_CAP       4096
#define XSTRIDE       36               // LDS x-row stride in dwords (144 B, 16B-aligned)

typedef __attribute__((ext_vector_type(8))) short bf16x8;
typedef __attribute__((ext_vector_type(4))) float f32x4;

__device__ inline uint32_t cvt_pk_bf16(float lo, float hi) {
    uint32_t r;
    asm("v_cvt_pk_bf16_f32 %0, %1, %2" : "=v"(r) : "v"(lo), "v"(hi));
    return r;
}

__device__ inline bf16x8 pack_frag(float a, float b, float c, float d,
                                   float e, float f, float g, float h) {
    union { uint32_t u[4]; bf16x8 v; } cv;
    cv.u[0] = cvt_pk_bf16(a, b);
    cv.u[1] = cvt_pk_bf16(c, d);
    cv.u[2] = cvt_pk_bf16(e, f);
    cv.u[3] = cvt_pk_bf16(g, h);
    return cv.v;
}

__device__ inline bf16x8 as_frag(uint4 u) {
    union { uint4 u; bf16x8 v; } cv; cv.u = u; return cv.v;
}

__device__ inline void pk_atomic(__half2* addr, float lo, float hi) {
    __half2 h = __floats2half2_rn(lo, hi);
    uint32_t u; __builtin_memcpy(&u, &h, 4);
    asm volatile("global_atomic_pk_add_f16 %0, %1, off" : : "v"(addr), "v"(u) : "memory");
}

// ---------------------------------------------------------------------------
// Pre-pack w into bf16 B-fragment layout: frag fid=(k*4+n)*2+kk, lane l holds
// B[kbase + (l>>4)*8 + j][n*16 + (l&15)], stored as uint4 at wp[fid*64 + l].
// ---------------------------------------------------------------------------
__global__ __launch_bounds__(256) void pack_w(
    const float* __restrict__ w, uint4* __restrict__ wp)
{
    const int tid = blockIdx.x * blockDim.x + threadIdx.x;
    if (tid >= KK * 8 * 64) return;
    const int lane = tid & 63;
    const int fid  = tid >> 6;
    const int k    = fid >> 3;
    const int n    = (fid & 7) >> 1;
    const int kk   = fid & 1;
    const int row  = lane & 15;
    const int kg   = lane >> 4;
    const int kbase = kk * 32 + kg * 8;

    const float* bp = w + (size_t)k * (INC * OUTC) + (size_t)kbase * OUTC + n * 16 + row;
    bf16x8 f = pack_frag(bp[0*OUTC], bp[1*OUTC], bp[2*OUTC], bp[3*OUTC],
                         bp[4*OUTC], bp[5*OUTC], bp[6*OUTC], bp[7*OUTC]);
    union { bf16x8 v; uint4 u; } cv; cv.v = f;
    wp[(size_t)fid * 64 + lane] = cv.u;
}

// ---------------------------------------------------------------------------
// Bin by (k, input-partition). Record = out_idx (18b) | local_in << 18 (7b).
// ---------------------------------------------------------------------------
__global__ __launch_bounds__(256) void scatter_pairs(
    const int* __restrict__ kin, const int* __restrict__ kout,
    uint32_t* __restrict__ cnt, uint32_t* __restrict__ bins,
    uint32_t* __restrict__ ovf_cnt, uint32_t* __restrict__ ovf)
{
    const int k = blockIdx.y;
    const int i = blockIdx.x * blockDim.x + threadIdx.x;
    if (i >= N_PAIRS) return;
    const int idx = k * N_PAIRS + i;
    const int out = kout[idx];
    const int in  = kin[idx];
    const int part  = in >> 7;
    const int local = in & 127;
    const int bin   = k * NPART + part;
    const uint32_t pos = atomicAdd(&cnt[bin], 1u);
    if (pos < BIN_CAP) {
        bins[(size_t)bin * BIN_CAP + pos] = (uint32_t)out | ((uint32_t)local << 18);
    } else {
        const uint32_t p2 = atomicAdd(ovf_cnt, 1u);
        if (p2 < OVF_CAP) ovf[p2] = (uint32_t)idx;
    }
}

// ---------------------------------------------------------------------------
// Input-binned conv. Block = one 128-row INPUT partition staged in LDS (bf16,
// stride 144B). Wave wid owns k = wid, wid+8, ... A-fragments come from LDS
// (no dependent global gather); rec loads are linear 64B reads, 6-deep
// unrolled. Scatter = packed-f16 global atomics (fire-and-forget).
// ---------------------------------------------------------------------------
__global__ __launch_bounds__(512) void conv_inpart(
    const float* __restrict__ x, const uint4* __restrict__ wp,
    const uint32_t* __restrict__ cnt, const uint32_t* __restrict__ bins,
    __half2* __restrict__ y2)
{
    __shared__ __align__(16) uint32_t xl[ROWS_PER_PART * XSTRIDE];  // 18432 B
    __shared__ int sh_cnt[KK];

    const int tid  = threadIdx.x;
    const int lane = tid & 63;
    const int wid  = tid >> 6;            // 0..7
    const int row  = lane & 15;
    const int kg   = lane >> 4;
    const int part = blockIdx.x;
    const int grow0 = part * ROWS_PER_PART;

    // ---- stage x rows [grow0, grow0+128) as bf16 into LDS ----
    #pragma unroll
    for (int i = 0; i < 8; ++i) {
        const int d  = tid + i * 512;     // 0..4095 (dword pairs of a row: 32/row)
        const int r  = d >> 5;
        const int c2 = d & 31;
        const int gr = grow0 + r;
        uint32_t v = 0;
        if (gr < N_VOX) {
            const float2 f = *(const float2*)(x + (size_t)gr * INC + c2 * 2);
            v = cvt_pk_bf16(f.x, f.y);
        }
        xl[r * XSTRIDE + c2] = v;
    }
    if (tid < KK) {
        const uint32_t c = cnt[tid * NPART + part];
        sh_cnt[tid] = (int)(c < BIN_CAP ? c : BIN_CAP);
    }
    __syncthreads();

    for (int k = wid; k < KK; k += 8) {
        const int cntk = sh_cnt[k];
        if (cntk == 0) continue;
        const int nch = (cntk + 15) >> 4;         // <= 6

        // B fragments for this k: 8 named regs (L2-hot)
        const size_t fb = (size_t)(k * 8) * 64 + lane;
        const uint4 b0 = wp[fb];        const uint4 b1 = wp[fb + 64];
        const uint4 b2 = wp[fb + 128];  const uint4 b3 = wp[fb + 192];
        const uint4 b4 = wp[fb + 256];  const uint4 b5 = wp[fb + 320];
        const uint4 b6 = wp[fb + 384];  const uint4 b7 = wp[fb + 448];

        const uint32_t* base = bins + (size_t)(k * NPART + part) * BIN_CAP;

        // phase 1: all rec loads (linear 64B lines, independent)
        uint32_t rr[6];
        #pragma unroll
        for (int ch = 0; ch < 6; ++ch)
            rr[ch] = (ch < nch) ? base[ch * 16 + row] : 0u;

        // phase 2: per chunk: LDS A-frag -> MFMA -> pk16 atomic scatter
        #pragma unroll
        for (int ch = 0; ch < 6; ++ch) {
            if (ch >= nch) continue;
            const int count = cntk - ch * 16;

            const uint4 ro = *(const uint4*)(base + ch * 16 + kg * 4);

            const int lrow = (int)((rr[ch] >> 18) & 127u);
            const uint32_t* xp = xl + lrow * XSTRIDE + kg * 4;
            const uint4 xa = *(const uint4*)(xp);
            const uint4 xbv = *(const uint4*)(xp + 16);
            const bf16x8 a0 = as_frag(xa);
            const bf16x8 a1 = as_frag(xbv);

            f32x4 c0 = {0,0,0,0}, c1 = {0,0,0,0}, c2 = {0,0,0,0}, c3 = {0,0,0,0};
            c0 = __builtin_amdgcn_mfma_f32_16x16x32_bf16(a0, as_frag(b0), c0, 0, 0, 0);
            c0 = __builtin_amdgcn_mfma_f32_16x16x32_bf16(a1, as_frag(b1), c0, 0, 0, 0);
            c1 = __builtin_amdgcn_mfma_f32_16x16x32_bf16(a0, as_frag(b2), c1, 0, 0, 0);
            c1 = __builtin_amdgcn_mfma_f32_16x16x32_bf16(a1, as_frag(b3), c1, 0, 0, 0);
            c2 = __builtin_amdgcn_mfma_f32_16x16x32_bf16(a0, as_frag(b4), c2, 0, 0, 0);
            c2 = __builtin_amdgcn_mfma_f32_16x16x32_bf16(a1, as_frag(b5), c2, 0, 0, 0);
            c3 = __builtin_amdgcn_mfma_f32_16x16x32_bf16(a0, as_frag(b6), c3, 0, 0, 0);
            c3 = __builtin_amdgcn_mfma_f32_16x16x32_bf16(a1, as_frag(b7), c3, 0, 0, 0);

            // scatter: D row = kg*4+j -> out idx from ro[j]; col = n*16 + row
            const uint32_t r0 = ro.x, r1 = ro.y, r2 = ro.z, r3 = ro.w;
            #pragma unroll
            for (int j = 0; j < 4; ++j) {
                const uint32_t rj = (j == 0) ? r0 : (j == 1) ? r1 : (j == 2) ? r2 : r3;
                if (kg * 4 + j < count) {   // uniform across the 16-lane group
                    const int out = (int)(rj & 0x3FFFFu);
                    __half2* rbase = y2 + (size_t)out * (OUTC/2) + (row >> 1);
                    const float v0 = c0[j], p0 = __shfl_xor(v0, 1);
                    const float v1 = c1[j], p1 = __shfl_xor(v1, 1);
                    const float v2 = c2[j], p2 = __shfl_xor(v2, 1);
                    const float v3 = c3[j], p3 = __shfl_xor(v3, 1);
                    if (!(lane & 1)) {
                        pk_atomic(rbase + 0,  v0, p0);
                        pk_atomic(rbase + 8,  v1, p1);
                        pk_atomic(rbase + 16, v2, p2);
                        pk_atomic(rbase + 24, v3, p3);
                    }
                }
            }
        }
    }
}

// ---------------------------------------------------------------------------
// Overflow fixup (expected ~tens of entries): parallel over entries.
// ---------------------------------------------------------------------------
__global__ __launch_bounds__(64) void ovf_fix16(
    const float* __restrict__ x, const float* __restrict__ w,
    const int* __restrict__ kin, const int* __restrict__ kout,
    const uint32_t* __restrict__ ovf_cnt, const uint32_t* __restrict__ ovf,
    __half2* __restrict__ y2)
{
    const int t = threadIdx.x;                 // 64 threads, t = channel
    const int n = (int)min(*ovf_cnt, (uint32_t)OVF_CAP);
    for (int i = blockIdx.x; i < n; i += gridDim.x) {
        const int idx = (int)ovf[i];
        const int k   = idx / N_PAIRS;
        const int in  = kin[idx];
        const int out = kout[idx];
        float acc = 0.f;
        for (int d = 0; d < INC; ++d)
            acc = fmaf(x[(size_t)in * INC + d], w[(size_t)k * INC * OUTC + d * OUTC + t], acc);
        const float p = __shfl_xor(acc, 1);
        if (!(t & 1)) pk_atomic(y2 + (size_t)out * (OUTC/2) + (t >> 1), acc, p);
    }
}

// ---------------------------------------------------------------------------
// BN stats / finalize / apply for fp16 accumulator
// ---------------------------------------------------------------------------
__global__ __launch_bounds__(256) void bn_reduce16(
    const __half2* __restrict__ y2, float* __restrict__ stats)
{
    __shared__ float s0a[256], s1a[256], q0a[256], q1a[256];

    const int c2 = threadIdx.x & 31;
    const int row0 = (blockIdx.x * blockDim.x + threadIdx.x) >> 5;
    const int rstride = (gridDim.x * blockDim.x) >> 5;

    float s0 = 0.f, s1 = 0.f, q0 = 0.f, q1 = 0.f;
    for (int r = row0; r < N_VOX; r += rstride) {
        const float2 v = __half22float2(y2[(size_t)r * 32 + c2]);
        s0 += v.x; q0 += v.x * v.x;
        s1 += v.y; q1 += v.y * v.y;
    }
    s0a[threadIdx.x] = s0; s1a[threadIdx.x] = s1;
    q0a[threadIdx.x] = q0; q1a[threadIdx.x] = q1;
    __syncthreads();

    if (threadIdx.x < 64) {
        const int c = threadIdx.x, p = c >> 1, b = c & 1;
        float ts = 0.f, tq = 0.f;
        #pragma unroll
        for (int g = 0; g < 8; ++g) {
            ts += b ? s1a[g * 32 + p] : s0a[g * 32 + p];
            tq += b ? q1a[g * 32 + p] : q0a[g * 32 + p];
        }
        atomicAdd(&stats[c], ts);
        atomicAdd(&stats[64 + c], tq);
    }
}

__global__ void bn_finalize(
    const float* __restrict__ stats, const float* __restrict__ gamma,
    const float* __restrict__ beta, float* __restrict__ coef)
{
    const int c = threadIdx.x;
    if (c < 64) {
        const float inv_n = 1.0f / (float)N_VOX;
        const float mean  = stats[c] * inv_n;
        const float var   = stats[64 + c] * inv_n - mean * mean;
        const float scale = gamma[c] * rsqrtf(var + BN_EPS);
        coef[c]      = scale;
        coef[64 + c] = beta[c] - mean * scale;
    }
}

__global__ __launch_bounds__(256) void bn_apply16(
    const __half2* __restrict__ y2, const float* __restrict__ coef,
    float2* __restrict__ out2)
{
    const size_t total2 = (size_t)N_VOX * 32;
    size_t i = (size_t)blockIdx.x * blockDim.x + threadIdx.x;
    const size_t stride = (size_t)gridDim.x * blockDim.x;

    const int c2 = (int)(i & 31);
    const float sc0 = coef[2*c2], sh0 = coef[64 + 2*c2];
    const float sc1 = coef[2*c2 + 1], sh1 = coef[64 + 2*c2 + 1];

    for (; i < total2; i += stride) {
        const float2 v = __half22float2(y2[i]);
        float2 o;
        o.x = fmaxf(0.f, fmaf(v.x, sc0, sh0));
        o.y = fmaxf(0.f, fmaf(v.y, sc1, sh1));
        out2[i] = o;
    }
}

// ==================== fallback tier: unbinned fp16 pk-atomic path ==========
__global__ __launch_bounds__(256) void conv_mfma16(
    const float* __restrict__ x, const float* __restrict__ w,
    const int* __restrict__ kin, const int* __restrict__ kout,
    __half2* __restrict__ y2)
{
    const int lane = threadIdx.x & 63;
    const int wid  = threadIdx.x >> 6;
    const int k    = blockIdx.y;
    const int row  = lane & 15;
    const int kg   = lane >> 4;

    const float* wk = w + (size_t)k * (INC * OUTC);

    bf16x8 bfrag[4][2];
    #pragma unroll
    for (int n = 0; n < 4; ++n) {
        #pragma unroll
        for (int kk = 0; kk < 2; ++kk) {
            const int kbase = kk * 32 + kg * 8;
            const float* bp = wk + (size_t)kbase * OUTC + n * 16 + row;
            bfrag[n][kk] = pack_frag(bp[0*OUTC], bp[1*OUTC], bp[2*OUTC], bp[3*OUTC],
                                     bp[4*OUTC], bp[5*OUTC], bp[6*OUTC], bp[7*OUTC]);
        }
    }

    const int* kin_k  = kin  + (size_t)k * N_PAIRS;
    const int* kout_k = kout + (size_t)k * N_PAIRS;

    const int NCHUNK = N_PAIRS / 16;
    const int nwaves = gridDim.x * 4;

    for (int ch = blockIdx.x * 4 + wid; ch < NCHUNK; ch += nwaves) {
        const int e0 = ch * 16;
        const int in_idx = kin_k[e0 + row];
        const int4 oi = *(const int4*)(kout_k + e0 + kg * 4);

        const float* xr = x + (size_t)in_idx * INC + kg * 8;
        bf16x8 afrag[2];
        #pragma unroll
        for (int kk = 0; kk < 2; ++kk) {
            const f32x4 a0 = *(const f32x4*)(xr + kk * 32);
            const f32x4 a1 = *(const f32x4*)(xr + kk * 32 + 4);
            afrag[kk] = pack_frag(a0.x, a0.y, a0.z, a0.w, a1.x, a1.y, a1.z, a1.w);
        }

        f32x4 acc[4] = {{0,0,0,0},{0,0,0,0},{0,0,0,0},{0,0,0,0}};
        #pragma unroll
        for (int n = 0; n < 4; ++n) {
            acc[n] = __builtin_amdgcn_mfma_f32_16x16x32_bf16(afrag[0], bfrag[n][0], acc[n], 0, 0, 0);
            acc[n] = __builtin_amdgcn_mfma_f32_16x16x32_bf16(afrag[1], bfrag[n][1], acc[n], 0, 0, 0);
        }

        const int orow[4] = {oi.x, oi.y, oi.z, oi.w};
        #pragma unroll
        for (int j = 0; j < 4; ++j) {
            __half2* rbase = y2 + (size_t)orow[j] * (OUTC/2) + (row >> 1);
            #pragma unroll
            for (int n = 0; n < 4; ++n) {
                const float v = acc[n][j];
                const float p = __shfl_xor(v, 1);
                if (!(lane & 1)) pk_atomic(rbase + n * 8, v, p);
            }
        }
    }
}

extern "C" void kernel_launch(void* const* d_in, const int* in_sizes, int n_in,
                              void* d_out, int out_size, void* d_ws, size_t ws_size,
                              hipStream_t stream)
{
    const float* x     = (const float*)d_in[0];
    const float* w     = (const float*)d_in[1];
    const float* gamma = (const float*)d_in[2];
    const float* beta  = (const float*)d_in[3];
    const int*   kin   = (const int*)d_in[4];
    const int*   kout  = (const int*)d_in[5];

    // Tier A ws layout (bytes)
    const size_t off_y2    = 0;                                   // 25,600,000
    const size_t off_cnt   = 25600000;                            // 168,832
    const size_t off_ovfc  = 25768832;                            // 64
    const size_t off_ovf   = 25768896;                            // 16,384
    const size_t off_stats = 25785280;                            // 512
    const size_t off_coef  = 25785792;                            // 512
    const size_t off_wp    = 25786304;                            // 221,184
    const size_t off_bins  = 26007488;                            // 16,205,184
    const size_t needA     = off_bins + (size_t)NBIN * BIN_CAP * 4;   // ~42.2 MB

    const size_t y16_bytes = (size_t)N_VOX * OUTC * sizeof(__half);   // 25.6 MB
    const size_t needB = y16_bytes + 1024;

    if (ws_size >= needA) {
        __half2*  y2      = (__half2*)((char*)d_ws + off_y2);
        uint32_t* cnt     = (uint32_t*)((char*)d_ws + off_cnt);
        uint32_t* ovfc    = (uint32_t*)((char*)d_ws + off_ovfc);
        uint32_t* ovf     = (uint32_t*)((char*)d_ws + off_ovf);
        float*    stats   = (float*)((char*)d_ws + off_stats);
        float*    coef    = (float*)((char*)d_ws + off_coef);
        uint4*    wp      = (uint4*)((char*)d_ws + off_wp);
        uint32_t* bins    = (uint32_t*)((char*)d_ws + off_bins);

        // zero y2 + cnt + ovf + stats in one shot
        hipMemsetAsync(d_ws, 0, off_coef, stream);

        pack_w<<<54, 256, 0, stream>>>(w, wp);
        scatter_pairs<<<dim3((N_PAIRS + 255) / 256, KK), 256, 0, stream>>>(
            kin, kout, cnt, bins, ovfc, ovf);
        conv_inpart<<<NPART, 512, 0, stream>>>(x, wp, cnt, bins, y2);
        ovf_fix16<<<128, 64, 0, stream>>>(x, w, kin, kout, ovfc, ovf, y2);
        bn_reduce16<<<512, 256, 0, stream>>>(y2, stats);
        bn_finalize<<<1, 64, 0, stream>>>(stats, gamma, beta, coef);
        bn_apply16<<<2048, 256, 0, stream>>>(y2, coef, (float2*)d_out);
    } else if (ws_size >= needB) {
        // unbinned fp16 packed-atomic path (proven 556 us conv)
        __half2* y2   = (__half2*)d_ws;
        float* stats  = (float*)((char*)d_ws + y16_bytes);
        float* coef   = stats + 128;

        hipMemsetAsync(y2, 0, y16_bytes, stream);
        hipMemsetAsync(stats, 0, 128 * sizeof(float), stream);

        conv_mfma16<<<dim3(64, KK), 256, 0, stream>>>(x, w, kin, kout, y2);
        bn_reduce16<<<512, 256, 0, stream>>>(y2, stats);
        bn_finalize<<<1, 64, 0, stream>>>(stats, gamma, beta, coef);
        bn_apply16<<<2048, 256, 0, stream>>>(y2, coef, (float2*)d_out);
    }
}